// Round 1
// baseline (636.379 us; speedup 1.0000x reference)
//
#include <hip/hip_runtime.h>
#include <cstddef>
#include <cstdint>

// ---------------------------------------------------------------------------
// GraphNeuralNetworkRiskManager: 2x GraphConv (sum-agg) + GAT attention + FC
// N=50000 nodes, E=800000 edges, F_IN=HID=128, F_OUT=2, all fp32.
//
// Structure:
//   1. Build CSR by destination on device (int histogram, 1-block scan,
//      int-atomic scatter). No float atomics anywhere.
//   2. agg = csr_sum(x);      h1 = relu(x@W1r + agg@W1n + b1)   (fused GEMM)
//   3. agg2 = csr_sum(h1);    h2 = relu(h1@W2r + agg2@W2n + b2)
//   4. ht = h2@Wa;  s_src = ht@a_src, s_dst = ht@a_dst
//   5. per-node fused attention: segment max, denom, weighted PV aggregation
//      (scores recomputed per phase -- cheaper than storing 800k floats x3)
//   6. out = out_h @ Wfc + bfc
// ---------------------------------------------------------------------------

#define LANES 64

// ---------------- CSR build ----------------

__global__ void hist_kernel(const int* __restrict__ ei, int E, int* __restrict__ cnt) {
  int e = blockIdx.x * blockDim.x + threadIdx.x;
  if (e < E) atomicAdd(&cnt[ei[E + e]], 1);  // dst = ei[E+e]
}

// exclusive prefix sum of cnt[0..n-1] -> ofs[0..n], single block of 1024
__global__ void scan_kernel(const int* __restrict__ cnt, int* __restrict__ ofs, int n) {
  __shared__ int wsum[16];
  __shared__ int carry;
  int tid = threadIdx.x;
  int lane = tid & 63;
  int wid = tid >> 6;
  if (tid == 0) carry = 0;
  __syncthreads();
  for (int base = 0; base < n; base += 1024) {
    int i = base + tid;
    int v = (i < n) ? cnt[i] : 0;
    // wave-inclusive scan
    int x = v;
    #pragma unroll
    for (int d = 1; d < 64; d <<= 1) {
      int y = __shfl_up(x, d);
      if (lane >= d) x += y;
    }
    if (lane == 63) wsum[wid] = x;
    __syncthreads();
    if (wid == 0) {
      int s = (lane < 16) ? wsum[lane] : 0;
      #pragma unroll
      for (int d = 1; d < 16; d <<= 1) {
        int y = __shfl_up(s, d);
        if (lane >= d) s += y;
      }
      if (lane < 16) wsum[lane] = s;  // inclusive wave sums
    }
    __syncthreads();
    int waveoff = (wid > 0) ? wsum[wid - 1] : 0;
    int incl = x + waveoff;
    int total = wsum[15];
    int c = carry;
    if (i < n) ofs[i] = c + incl - v;  // exclusive
    __syncthreads();                   // everyone done reading carry/wsum
    if (tid == 0) carry = c + total;
    __syncthreads();
  }
  if (tid == 0) ofs[n] = carry;
}

__global__ void scatter_kernel(const int* __restrict__ ei, int E,
                               const int* __restrict__ ofs, int* __restrict__ cur,
                               int* __restrict__ csr) {
  int e = blockIdx.x * blockDim.x + threadIdx.x;
  if (e < E) {
    int d = ei[E + e];
    int p = ofs[d] + atomicAdd(&cur[d], 1);
    csr[p] = ei[e];  // src
  }
}

// ---------------- CSR sum-aggregation: one wave per node ----------------

__global__ __launch_bounds__(256) void agg_kernel(
    const float* __restrict__ X, const int* __restrict__ csr,
    const int* __restrict__ ofs, float* __restrict__ out, int N) {
  int wave = (blockIdx.x * blockDim.x + threadIdx.x) >> 6;
  int lane = threadIdx.x & 63;
  if (wave >= N) return;
  int beg = ofs[wave], end = ofs[wave + 1];
  float a0 = 0.f, a1 = 0.f;
  int p = beg;
  for (; p + 1 < end; p += 2) {
    int s0 = csr[p], s1 = csr[p + 1];
    const float* r0 = X + (size_t)s0 * 128;
    const float* r1 = X + (size_t)s1 * 128;
    a0 += r0[lane];      a1 += r0[lane + 64];
    a0 += r1[lane];      a1 += r1[lane + 64];
  }
  if (p < end) {
    const float* r0 = X + (size_t)csr[p] * 128;
    a0 += r0[lane];      a1 += r0[lane + 64];
  }
  out[(size_t)wave * 128 + lane] = a0;
  out[(size_t)wave * 128 + 64 + lane] = a1;
}

// ---------------- fused dual-A GEMM: C = relu(A1@W1 + A2@W2 + b) ----------------
// M x 128 output, K = 128 per source. 64-row tile per block, 256 threads,
// per-thread 8 rows x 4 cols register tile, K staged 32-wide in LDS.

template <bool FUSED, bool RELU, bool BIAS>
__global__ __launch_bounds__(256) void gemm_kernel(
    const float* __restrict__ A1, const float* __restrict__ W1,
    const float* __restrict__ A2, const float* __restrict__ W2,
    const float* __restrict__ bias, float* __restrict__ C, int M) {
  __shared__ float As[64][32];
  __shared__ float Ws[32][128];
  int t = threadIdx.x;
  int r0 = (t >> 5) * 8;
  int c0 = (t & 31) * 4;
  int rowBase = blockIdx.x * 64;
  float acc[8][4] = {};

  for (int s = 0; s < (FUSED ? 2 : 1); ++s) {
    const float* A = (s == 0) ? A1 : A2;
    const float* W = (s == 0) ? W1 : W2;
    for (int kc = 0; kc < 128; kc += 32) {
      // stage A tile: 64x32 floats = 512 float4, 2 per thread
      #pragma unroll
      for (int j = 0; j < 2; ++j) {
        int id = t + j * 256;
        int r = id >> 3, kk = (id & 7) * 4;
        int row = rowBase + r;
        float4 v = make_float4(0.f, 0.f, 0.f, 0.f);
        if (row < M) v = *(const float4*)(A + (size_t)row * 128 + kc + kk);
        *(float4*)&As[r][kk] = v;
      }
      // stage W tile: 32x128 floats = 1024 float4, 4 per thread
      #pragma unroll
      for (int j = 0; j < 4; ++j) {
        int id = t + j * 256;
        int kk = id >> 5, cc = (id & 31) * 4;
        *(float4*)&Ws[kk][cc] = *(const float4*)(W + (size_t)(kc + kk) * 128 + cc);
      }
      __syncthreads();
      #pragma unroll
      for (int k4 = 0; k4 < 8; ++k4) {
        float4 w0 = *(float4*)&Ws[k4 * 4 + 0][c0];
        float4 w1 = *(float4*)&Ws[k4 * 4 + 1][c0];
        float4 w2 = *(float4*)&Ws[k4 * 4 + 2][c0];
        float4 w3 = *(float4*)&Ws[k4 * 4 + 3][c0];
        #pragma unroll
        for (int i = 0; i < 8; ++i) {
          float4 a = *(float4*)&As[r0 + i][k4 * 4];
          acc[i][0] += a.x * w0.x + a.y * w1.x + a.z * w2.x + a.w * w3.x;
          acc[i][1] += a.x * w0.y + a.y * w1.y + a.z * w2.y + a.w * w3.y;
          acc[i][2] += a.x * w0.z + a.y * w1.z + a.z * w2.z + a.w * w3.z;
          acc[i][3] += a.x * w0.w + a.y * w1.w + a.z * w2.w + a.w * w3.w;
        }
      }
      __syncthreads();
    }
  }

  #pragma unroll
  for (int i = 0; i < 8; ++i) {
    int row = rowBase + r0 + i;
    if (row < M) {
      float4 o;
      o.x = acc[i][0]; o.y = acc[i][1]; o.z = acc[i][2]; o.w = acc[i][3];
      if (BIAS) {
        o.x += bias[c0 + 0]; o.y += bias[c0 + 1];
        o.z += bias[c0 + 2]; o.w += bias[c0 + 3];
      }
      if (RELU) {
        o.x = fmaxf(o.x, 0.f); o.y = fmaxf(o.y, 0.f);
        o.z = fmaxf(o.z, 0.f); o.w = fmaxf(o.w, 0.f);
      }
      *(float4*)(C + (size_t)row * 128 + c0) = o;
    }
  }
}

// ---------------- per-node dots: s_src = ht.a_src, s_dst = ht.a_dst ----------------

__global__ __launch_bounds__(256) void dots_kernel(
    const float* __restrict__ HT, const float* __restrict__ a_src,
    const float* __restrict__ a_dst, float* __restrict__ ssrc,
    float* __restrict__ sdst, int N) {
  int n = (blockIdx.x * blockDim.x + threadIdx.x) >> 6;
  int lane = threadIdx.x & 63;
  if (n >= N) return;
  float h0 = HT[(size_t)n * 128 + lane];
  float h1 = HT[(size_t)n * 128 + 64 + lane];
  float vs = h0 * a_src[lane] + h1 * a_src[64 + lane];
  float vd = h0 * a_dst[lane] + h1 * a_dst[64 + lane];
  #pragma unroll
  for (int d = 32; d > 0; d >>= 1) {
    vs += __shfl_xor(vs, d);
    vd += __shfl_xor(vd, d);
  }
  if (lane == 0) { ssrc[n] = vs; sdst[n] = vd; }
}

// ---------------- fused attention: segment softmax + weighted aggregation ----------------

__global__ __launch_bounds__(256) void attn_kernel(
    const float* __restrict__ HT, const int* __restrict__ csr,
    const int* __restrict__ ofs, const float* __restrict__ ssrc,
    const float* __restrict__ sdst, float* __restrict__ outh, int N) {
  int n = (blockIdx.x * blockDim.x + threadIdx.x) >> 6;
  int lane = threadIdx.x & 63;
  if (n >= N) return;
  int beg = ofs[n], end = ofs[n + 1];
  float sd = sdst[n];

  // phase 1: segment max (lanes over edges)
  float mymax = -3.4e38f;
  for (int p = beg + lane; p < end; p += 64) {
    float e = ssrc[csr[p]] + sd;
    e = (e >= 0.f) ? e : 0.2f * e;
    mymax = fmaxf(mymax, e);
  }
  #pragma unroll
  for (int d = 32; d > 0; d >>= 1) mymax = fmaxf(mymax, __shfl_xor(mymax, d));

  // phase 2: denom
  float mysum = 0.f;
  for (int p = beg + lane; p < end; p += 64) {
    float e = ssrc[csr[p]] + sd;
    e = (e >= 0.f) ? e : 0.2f * e;
    mysum += __expf(e - mymax);
  }
  #pragma unroll
  for (int d = 32; d > 0; d >>= 1) mysum += __shfl_xor(mysum, d);
  float inv = 1.0f / (mysum + 1e-16f);

  // phase 3: weighted aggregation (lanes over features, serial over edges)
  float a0 = 0.f, a1 = 0.f;
  for (int p = beg; p < end; ++p) {
    int s = csr[p];
    float e = ssrc[s] + sd;
    e = (e >= 0.f) ? e : 0.2f * e;
    float w = __expf(e - mymax) * inv;
    const float* row = HT + (size_t)s * 128;
    a0 += w * row[lane];
    a1 += w * row[64 + lane];
  }
  outh[(size_t)n * 128 + lane] = a0;
  outh[(size_t)n * 128 + 64 + lane] = a1;
}

// ---------------- final FC: out = out_h @ Wfc + bfc  (128 -> 2) ----------------

__global__ __launch_bounds__(256) void fc_kernel(
    const float* __restrict__ H, const float* __restrict__ Wfc,
    const float* __restrict__ bfc, float* __restrict__ out, int N) {
  int n = (blockIdx.x * blockDim.x + threadIdx.x) >> 6;
  int lane = threadIdx.x & 63;
  if (n >= N) return;
  float h0 = H[(size_t)n * 128 + lane];
  float h1 = H[(size_t)n * 128 + 64 + lane];
  float o0 = h0 * Wfc[lane * 2 + 0] + h1 * Wfc[(lane + 64) * 2 + 0];
  float o1 = h0 * Wfc[lane * 2 + 1] + h1 * Wfc[(lane + 64) * 2 + 1];
  #pragma unroll
  for (int d = 32; d > 0; d >>= 1) {
    o0 += __shfl_xor(o0, d);
    o1 += __shfl_xor(o1, d);
  }
  if (lane == 0) {
    out[(size_t)n * 2 + 0] = o0 + bfc[0];
    out[(size_t)n * 2 + 1] = o1 + bfc[1];
  }
}

// ---------------- launch ----------------

static inline size_t align_up(size_t x, size_t a) { return (x + a - 1) & ~(a - 1); }

extern "C" void kernel_launch(void* const* d_in, const int* in_sizes, int n_in,
                              void* d_out, int out_size, void* d_ws, size_t ws_size,
                              hipStream_t stream) {
  const float* x     = (const float*)d_in[0];
  const int*   ei    = (const int*)d_in[1];
  const float* W1r   = (const float*)d_in[2];
  const float* W1n   = (const float*)d_in[3];
  const float* b1    = (const float*)d_in[4];
  const float* W2r   = (const float*)d_in[5];
  const float* W2n   = (const float*)d_in[6];
  const float* b2    = (const float*)d_in[7];
  const float* Wa    = (const float*)d_in[8];
  const float* a_src = (const float*)d_in[9];
  const float* a_dst = (const float*)d_in[10];
  const float* Wfc   = (const float*)d_in[11];
  const float* bfc   = (const float*)d_in[12];

  const int N = in_sizes[0] / 128;   // 50000
  const int E = in_sizes[1] / 2;     // 800000

  // workspace carve-up
  char* ws = (char*)d_ws;
  size_t off = 0;
  auto take = [&](size_t bytes) {
    char* p = ws + off;
    off = align_up(off + bytes, 256);
    return p;
  };
  int*   ofs  = (int*)take((size_t)(N + 1) * 4);
  int*   cnt  = (int*)take((size_t)N * 4);
  int*   cur  = (int*)take((size_t)N * 4);
  int*   csr  = (int*)take((size_t)E * 4);
  float* ssrc = (float*)take((size_t)N * 4);
  float* sdst = (float*)take((size_t)N * 4);
  float* bufA = (float*)take((size_t)N * 128 * 4);  // agg / agg2 / out_h
  float* bufB = (float*)take((size_t)N * 128 * 4);  // h1 / ht
  float* bufC = (float*)take((size_t)N * 128 * 4);  // h2

  hipMemsetAsync(cnt, 0, (size_t)N * 4, stream);
  hipMemsetAsync(cur, 0, (size_t)N * 4, stream);

  const int edgeBlocks = (E + 255) / 256;
  const int nodeBlocks = (N + 3) / 4;   // 4 waves per 256-thread block
  const int gemmBlocks = (N + 63) / 64;

  // CSR build
  hist_kernel<<<edgeBlocks, 256, 0, stream>>>(ei, E, cnt);
  scan_kernel<<<1, 1024, 0, stream>>>(cnt, ofs, N);
  scatter_kernel<<<edgeBlocks, 256, 0, stream>>>(ei, E, ofs, cur, csr);

  // layer 1
  agg_kernel<<<nodeBlocks, 256, 0, stream>>>(x, csr, ofs, bufA, N);
  gemm_kernel<true, true, true><<<gemmBlocks, 256, 0, stream>>>(
      x, W1r, bufA, W1n, b1, bufB, N);          // bufB = h1

  // layer 2
  agg_kernel<<<nodeBlocks, 256, 0, stream>>>(bufB, csr, ofs, bufA, N);
  gemm_kernel<true, true, true><<<gemmBlocks, 256, 0, stream>>>(
      bufB, W2r, bufA, W2n, b2, bufC, N);       // bufC = h2

  // attention transform
  gemm_kernel<false, false, false><<<gemmBlocks, 256, 0, stream>>>(
      bufC, Wa, nullptr, nullptr, nullptr, bufB, N);   // bufB = ht
  dots_kernel<<<nodeBlocks, 256, 0, stream>>>(bufB, a_src, a_dst, ssrc, sdst, N);
  attn_kernel<<<nodeBlocks, 256, 0, stream>>>(bufB, csr, ofs, ssrc, sdst, bufA, N);  // bufA = out_h

  // output FC
  fc_kernel<<<nodeBlocks, 256, 0, stream>>>(bufA, Wfc, bfc, (float*)d_out, N);
}

// Round 3
// 536.786 us; speedup vs baseline: 1.1855x; 1.1855x over previous
//
#include <hip/hip_runtime.h>
#include <cstddef>
#include <cstdint>

// ---------------------------------------------------------------------------
// GraphNeuralNetworkRiskManager: 2x GraphConv (sum-agg) + GAT attention + FC
// N=50000 nodes, E=800000 edges, F_IN=HID=128, F_OUT=2, fp32 in memory.
//
// Round 3: GEMMs via bf16x3 compensated MFMA (split a=ah+al, w=wh+wl;
// a*w ~= ah*wh + al*wh + ah*wl, error ~2^-18 rel -> fp32-grade accuracy at
// matrix-core speed). All node tensors stay fp32; gathers/softmax fp32.
// Barrier-free GEMM: 8 waves/block, each wave owns a 16-col group and keeps
// the full W column slice (hi+lo bf16) in registers.
// ---------------------------------------------------------------------------

typedef __attribute__((ext_vector_type(8))) short short8;
typedef __attribute__((ext_vector_type(4))) float f32x4;

__device__ __forceinline__ ushort f2b(float f) {       // fp32 -> bf16 bits, RNE
  uint32_t u = __float_as_uint(f);
  u += 0x7fffu + ((u >> 16) & 1u);
  return (ushort)(u >> 16);
}
__device__ __forceinline__ float b2f(ushort h) {       // bf16 bits -> fp32
  return __uint_as_float(((uint32_t)h) << 16);
}

// ---------------- CSR build ----------------

__global__ void hist_kernel(const int* __restrict__ ei, int E, int* __restrict__ cnt) {
  int e = blockIdx.x * blockDim.x + threadIdx.x;
  if (e < E) atomicAdd(&cnt[ei[E + e]], 1);  // dst = ei[E+e]
}

// exclusive prefix sum of cnt[0..n-1] -> ofs[0..n], single block of 1024
__global__ void scan_kernel(const int* __restrict__ cnt, int* __restrict__ ofs, int n) {
  __shared__ int wsum[16];
  __shared__ int carry;
  int tid = threadIdx.x;
  int lane = tid & 63;
  int wid = tid >> 6;
  if (tid == 0) carry = 0;
  __syncthreads();
  for (int base = 0; base < n; base += 1024) {
    int i = base + tid;
    int v = (i < n) ? cnt[i] : 0;
    int x = v;
    #pragma unroll
    for (int d = 1; d < 64; d <<= 1) {
      int y = __shfl_up(x, d);
      if (lane >= d) x += y;
    }
    if (lane == 63) wsum[wid] = x;
    __syncthreads();
    if (wid == 0) {
      int s = (lane < 16) ? wsum[lane] : 0;
      #pragma unroll
      for (int d = 1; d < 16; d <<= 1) {
        int y = __shfl_up(s, d);
        if (lane >= d) s += y;
      }
      if (lane < 16) wsum[lane] = s;
    }
    __syncthreads();
    int waveoff = (wid > 0) ? wsum[wid - 1] : 0;
    int incl = x + waveoff;
    int total = wsum[15];
    int c = carry;
    if (i < n) ofs[i] = c + incl - v;
    __syncthreads();
    if (tid == 0) carry = c + total;
    __syncthreads();
  }
  if (tid == 0) ofs[n] = carry;
}

__global__ void scatter_kernel(const int* __restrict__ ei, int E,
                               const int* __restrict__ ofs, int* __restrict__ cur,
                               int* __restrict__ csr) {
  int e = blockIdx.x * blockDim.x + threadIdx.x;
  if (e < E) {
    int d = ei[E + e];
    int p = ofs[d] + atomicAdd(&cur[d], 1);
    csr[p] = ei[e];  // src
  }
}

// ---------------- CSR sum-aggregation: one wave per node (fp32) ----------------

__global__ __launch_bounds__(256) void agg_kernel(
    const float* __restrict__ X, const int* __restrict__ csr,
    const int* __restrict__ ofs, float* __restrict__ out, int N) {
  int wave = (blockIdx.x * blockDim.x + threadIdx.x) >> 6;
  int lane = threadIdx.x & 63;
  if (wave >= N) return;
  int beg = ofs[wave], end = ofs[wave + 1];
  float a0 = 0.f, a1 = 0.f;
  int p = beg;
  for (; p + 1 < end; p += 2) {
    int s0 = csr[p], s1 = csr[p + 1];
    const float* r0 = X + (size_t)s0 * 128;
    const float* r1 = X + (size_t)s1 * 128;
    a0 += r0[lane];      a1 += r0[lane + 64];
    a0 += r1[lane];      a1 += r1[lane + 64];
  }
  if (p < end) {
    const float* r0 = X + (size_t)csr[p] * 128;
    a0 += r0[lane];      a1 += r0[lane + 64];
  }
  out[(size_t)wave * 128 + lane] = a0;
  out[(size_t)wave * 128 + 64 + lane] = a1;
}

// ---------------- bf16x3 MFMA GEMM: C = act(A1@W1 [+ A2@W2] + b) ----------------
// M x 128, K = 128. 512 threads = 8 waves; wave w owns cols [16w,16w+16).
// W column slice held in registers as hi+lo bf16 (compensated split, done
// once). A rows loaded fp32 from global (L1-broadcast across waves), split
// in-register. 64-row tile per block. No LDS, no barriers.
// A frag (16x16x32): lane l -> row (l&15), k = (l>>4)*8 + b.
// D frag: col = l&15, row = (l>>4)*4 + reg   [validated round 2].

template <bool FUSED, bool RELU, bool BIAS>
__global__ __launch_bounds__(512) void mgemm_kernel(
    const float* __restrict__ A1, const float* __restrict__ W1,
    const float* __restrict__ A2, const float* __restrict__ W2,
    const float* __restrict__ bias, float* __restrict__ C, int M) {
  int l = threadIdx.x & 63;
  int w = threadIdx.x >> 6;
  int j = (w << 4) + (l & 15);      // output column
  int krow0 = (l >> 4) * 8;         // k offset within 32-wide k-step
  int rowBase = blockIdx.x * 64;

  // W fragments, compensated split: [src][kstep]
  short8 wh[2][4], wl[2][4];
  #pragma unroll
  for (int s = 0; s < (FUSED ? 2 : 1); ++s) {
    const float* W = (s == 0) ? W1 : W2;
    #pragma unroll
    for (int ks = 0; ks < 4; ++ks) {
      short8 fh, fl;
      #pragma unroll
      for (int b = 0; b < 8; ++b) {
        float v = W[(size_t)(ks * 32 + krow0 + b) * 128 + j];
        ushort h = f2b(v);
        float rem = v - b2f(h);
        fh[b] = (short)h;
        fl[b] = (short)f2b(rem);
      }
      wh[s][ks] = fh;
      wl[s][ks] = fl;
    }
  }

  f32x4 acc[4] = {{0.f, 0.f, 0.f, 0.f}, {0.f, 0.f, 0.f, 0.f},
                  {0.f, 0.f, 0.f, 0.f}, {0.f, 0.f, 0.f, 0.f}};

  #pragma unroll
  for (int rf = 0; rf < 4; ++rf) {
    int row = rowBase + rf * 16 + (l & 15);
    if (row >= M) row = M - 1;                 // clamp (tail); writes are masked
    #pragma unroll
    for (int s = 0; s < (FUSED ? 2 : 1); ++s) {
      const float* A = (s == 0) ? A1 : A2;
      const float* ar = A + (size_t)row * 128 + krow0;
      #pragma unroll
      for (int ks = 0; ks < 4; ++ks) {
        float4 v0 = *(const float4*)(ar + ks * 32);
        float4 v1 = *(const float4*)(ar + ks * 32 + 4);
        float av[8] = {v0.x, v0.y, v0.z, v0.w, v1.x, v1.y, v1.z, v1.w};
        short8 ah, al;
        #pragma unroll
        for (int b = 0; b < 8; ++b) {
          ushort h = f2b(av[b]);
          float rem = av[b] - b2f(h);
          ah[b] = (short)h;
          al[b] = (short)f2b(rem);
        }
        acc[rf] = __builtin_amdgcn_mfma_f32_16x16x32_bf16(al, wh[s][ks], acc[rf], 0, 0, 0);
        acc[rf] = __builtin_amdgcn_mfma_f32_16x16x32_bf16(ah, wl[s][ks], acc[rf], 0, 0, 0);
        acc[rf] = __builtin_amdgcn_mfma_f32_16x16x32_bf16(ah, wh[s][ks], acc[rf], 0, 0, 0);
      }
    }
  }

  float bj = BIAS ? bias[j] : 0.f;
  #pragma unroll
  for (int rf = 0; rf < 4; ++rf) {
    int rbase = rowBase + rf * 16 + (l >> 4) * 4;
    #pragma unroll
    for (int r = 0; r < 4; ++r) {
      int row = rbase + r;
      if (row < M) {
        float v = acc[rf][r];
        if (BIAS) v += bj;
        if (RELU) v = fmaxf(v, 0.f);
        C[(size_t)row * 128 + j] = v;
      }
    }
  }
}

// ---------------- per-node dots: s_src = ht.a_src, s_dst = ht.a_dst ----------------

__global__ __launch_bounds__(256) void dots_kernel(
    const float* __restrict__ HT, const float* __restrict__ a_src,
    const float* __restrict__ a_dst, float* __restrict__ ssrc,
    float* __restrict__ sdst, int N) {
  int n = (blockIdx.x * blockDim.x + threadIdx.x) >> 6;
  int lane = threadIdx.x & 63;
  if (n >= N) return;
  float h0 = HT[(size_t)n * 128 + lane];
  float h1 = HT[(size_t)n * 128 + 64 + lane];
  float vs = h0 * a_src[lane] + h1 * a_src[64 + lane];
  float vd = h0 * a_dst[lane] + h1 * a_dst[64 + lane];
  #pragma unroll
  for (int d = 32; d > 0; d >>= 1) {
    vs += __shfl_xor(vs, d);
    vd += __shfl_xor(vd, d);
  }
  if (lane == 0) { ssrc[n] = vs; sdst[n] = vd; }
}

// ---------------- fused attention: segment softmax + weighted aggregation ----------------

__global__ __launch_bounds__(256) void attn_kernel(
    const float* __restrict__ HT, const int* __restrict__ csr,
    const int* __restrict__ ofs, const float* __restrict__ ssrc,
    const float* __restrict__ sdst, float* __restrict__ outh, int N) {
  int n = (blockIdx.x * blockDim.x + threadIdx.x) >> 6;
  int lane = threadIdx.x & 63;
  if (n >= N) return;
  int beg = ofs[n], end = ofs[n + 1];
  float sd = sdst[n];

  // phase 1: segment max (lanes over edges)
  float mymax = -3.4e38f;
  for (int p = beg + lane; p < end; p += 64) {
    float e = ssrc[csr[p]] + sd;
    e = (e >= 0.f) ? e : 0.2f * e;
    mymax = fmaxf(mymax, e);
  }
  #pragma unroll
  for (int d = 32; d > 0; d >>= 1) mymax = fmaxf(mymax, __shfl_xor(mymax, d));

  // phase 2: denom
  float mysum = 0.f;
  for (int p = beg + lane; p < end; p += 64) {
    float e = ssrc[csr[p]] + sd;
    e = (e >= 0.f) ? e : 0.2f * e;
    mysum += __expf(e - mymax);
  }
  #pragma unroll
  for (int d = 32; d > 0; d >>= 1) mysum += __shfl_xor(mysum, d);
  float inv = 1.0f / (mysum + 1e-16f);

  // phase 3: weighted aggregation (lanes over features, serial over edges)
  float a0 = 0.f, a1 = 0.f;
  for (int p = beg; p < end; ++p) {
    int s = csr[p];
    float e = ssrc[s] + sd;
    e = (e >= 0.f) ? e : 0.2f * e;
    float wgt = __expf(e - mymax) * inv;
    const float* row = HT + (size_t)s * 128;
    a0 += wgt * row[lane];
    a1 += wgt * row[64 + lane];
  }
  outh[(size_t)n * 128 + lane] = a0;
  outh[(size_t)n * 128 + 64 + lane] = a1;
}

// ---------------- final FC: out = out_h @ Wfc + bfc  (128 -> 2) ----------------

__global__ __launch_bounds__(256) void fc_kernel(
    const float* __restrict__ H, const float* __restrict__ Wfc,
    const float* __restrict__ bfc, float* __restrict__ out, int N) {
  int n = (blockIdx.x * blockDim.x + threadIdx.x) >> 6;
  int lane = threadIdx.x & 63;
  if (n >= N) return;
  float h0 = H[(size_t)n * 128 + lane];
  float h1 = H[(size_t)n * 128 + 64 + lane];
  float o0 = h0 * Wfc[lane * 2 + 0] + h1 * Wfc[(lane + 64) * 2 + 0];
  float o1 = h0 * Wfc[lane * 2 + 1] + h1 * Wfc[(lane + 64) * 2 + 1];
  #pragma unroll
  for (int d = 32; d > 0; d >>= 1) {
    o0 += __shfl_xor(o0, d);
    o1 += __shfl_xor(o1, d);
  }
  if (lane == 0) {
    out[(size_t)n * 2 + 0] = o0 + bfc[0];
    out[(size_t)n * 2 + 1] = o1 + bfc[1];
  }
}

// ---------------- launch ----------------

static inline size_t align_up(size_t x, size_t a) { return (x + a - 1) & ~(a - 1); }

extern "C" void kernel_launch(void* const* d_in, const int* in_sizes, int n_in,
                              void* d_out, int out_size, void* d_ws, size_t ws_size,
                              hipStream_t stream) {
  const float* x     = (const float*)d_in[0];
  const int*   ei    = (const int*)d_in[1];
  const float* W1r   = (const float*)d_in[2];
  const float* W1n   = (const float*)d_in[3];
  const float* b1    = (const float*)d_in[4];
  const float* W2r   = (const float*)d_in[5];
  const float* W2n   = (const float*)d_in[6];
  const float* b2    = (const float*)d_in[7];
  const float* Wa    = (const float*)d_in[8];
  const float* a_src = (const float*)d_in[9];
  const float* a_dst = (const float*)d_in[10];
  const float* Wfc   = (const float*)d_in[11];
  const float* bfc   = (const float*)d_in[12];

  const int N = in_sizes[0] / 128;   // 50000
  const int E = in_sizes[1] / 2;     // 800000

  // workspace carve-up
  char* ws = (char*)d_ws;
  size_t off = 0;
  auto take = [&](size_t bytes) {
    char* p = ws + off;
    off = align_up(off + bytes, 256);
    return p;
  };
  int*   ofs  = (int*)take((size_t)(N + 1) * 4);
  int*   cnt  = (int*)take((size_t)N * 4);
  int*   cur  = (int*)take((size_t)N * 4);
  int*   csr  = (int*)take((size_t)E * 4);
  float* ssrc = (float*)take((size_t)N * 4);
  float* sdst = (float*)take((size_t)N * 4);
  float* bufA = (float*)take((size_t)N * 128 * 4);  // agg / agg2 / out_h
  float* bufB = (float*)take((size_t)N * 128 * 4);  // h1 / ht
  float* bufC = (float*)take((size_t)N * 128 * 4);  // h2

  hipMemsetAsync(cnt, 0, (size_t)N * 4, stream);
  hipMemsetAsync(cur, 0, (size_t)N * 4, stream);

  const int edgeBlocks = (E + 255) / 256;
  const int nodeBlocks = (N + 3) / 4;   // 4 waves per 256-thread block
  const int gemmBlocks = (N + 63) / 64;

  // CSR build
  hist_kernel<<<edgeBlocks, 256, 0, stream>>>(ei, E, cnt);
  scan_kernel<<<1, 1024, 0, stream>>>(cnt, ofs, N);
  scatter_kernel<<<edgeBlocks, 256, 0, stream>>>(ei, E, ofs, cur, csr);

  // layer 1
  agg_kernel<<<nodeBlocks, 256, 0, stream>>>(x, csr, ofs, bufA, N);
  mgemm_kernel<true, true, true><<<gemmBlocks, 512, 0, stream>>>(
      x, W1r, bufA, W1n, b1, bufB, N);          // bufB = h1

  // layer 2
  agg_kernel<<<nodeBlocks, 256, 0, stream>>>(bufB, csr, ofs, bufA, N);
  mgemm_kernel<true, true, true><<<gemmBlocks, 512, 0, stream>>>(
      bufB, W2r, bufA, W2n, b2, bufC, N);       // bufC = h2

  // attention transform: ht = h2@Wa
  mgemm_kernel<false, false, false><<<gemmBlocks, 512, 0, stream>>>(
      bufC, Wa, nullptr, nullptr, nullptr, bufB, N);   // bufB = ht
  dots_kernel<<<nodeBlocks, 256, 0, stream>>>(bufB, a_src, a_dst, ssrc, sdst, N);
  attn_kernel<<<nodeBlocks, 256, 0, stream>>>(bufB, csr, ofs, ssrc, sdst, bufA, N);  // bufA = out_h

  // output FC
  fc_kernel<<<nodeBlocks, 256, 0, stream>>>(bufA, Wfc, bfc, (float*)d_out, N);
}

// Round 4
// 440.530 us; speedup vs baseline: 1.4446x; 1.2185x over previous
//
#include <hip/hip_runtime.h>
#include <cstddef>
#include <cstdint>

// ---------------------------------------------------------------------------
// GraphNeuralNetworkRiskManager: 2x GraphConv (sum-agg) + GAT attention + FC
// N=50000 nodes, E=800000 edges, F_IN=HID=128, F_OUT=2.
//
// Round 4: all node tensors stored as bf16 hi+lo pairs (hi=bf16(v),
// lo=bf16(v-hi) -> 2^-18 rel accuracy). GEMMs read hi/lo directly (3 MFMAs
// per product, zero split VALU in the loop). Gather kernels (agg, attn PV)
// read hi only with 4-edge-group 16B loads + cross-lane reduce. Weights
// split in-register per wave (once). Softmax fp32.
// ---------------------------------------------------------------------------

typedef __attribute__((ext_vector_type(8))) short short8;
typedef __attribute__((ext_vector_type(4))) float f32x4;

__device__ __forceinline__ ushort f2b(float f) {       // fp32 -> bf16 bits, RNE
  uint32_t u = __float_as_uint(f);
  u += 0x7fffu + ((u >> 16) & 1u);
  return (ushort)(u >> 16);
}
__device__ __forceinline__ float b2f(ushort h) {       // bf16 bits -> fp32
  return __uint_as_float(((uint32_t)h) << 16);
}

// ---------------- fp32 -> (hi, lo) bf16 split of x ----------------

__global__ __launch_bounds__(256) void split_kernel(
    const float* __restrict__ in, ushort* __restrict__ hi,
    ushort* __restrict__ lo, int n) {
  int i = (blockIdx.x * blockDim.x + threadIdx.x) * 8;
  if (i >= n) return;
  float4 v0 = *(const float4*)(in + i);
  float4 v1 = *(const float4*)(in + i + 4);
  float v[8] = {v0.x, v0.y, v0.z, v0.w, v1.x, v1.y, v1.z, v1.w};
  short8 h, l;
  #pragma unroll
  for (int b = 0; b < 8; ++b) {
    ushort hh = f2b(v[b]);
    h[b] = (short)hh;
    l[b] = (short)f2b(v[b] - b2f(hh));
  }
  *(short8*)(hi + i) = h;
  *(short8*)(lo + i) = l;
}

// ---------------- CSR build ----------------

__global__ void hist_kernel(const int* __restrict__ ei, int E, int* __restrict__ cnt) {
  int e = blockIdx.x * blockDim.x + threadIdx.x;
  if (e < E) atomicAdd(&cnt[ei[E + e]], 1);  // dst = ei[E+e]
}

// exclusive prefix sum of cnt[0..n-1] -> ofs[0..n], single block of 1024
__global__ void scan_kernel(const int* __restrict__ cnt, int* __restrict__ ofs, int n) {
  __shared__ int wsum[16];
  __shared__ int carry;
  int tid = threadIdx.x;
  int lane = tid & 63;
  int wid = tid >> 6;
  if (tid == 0) carry = 0;
  __syncthreads();
  for (int base = 0; base < n; base += 1024) {
    int i = base + tid;
    int v = (i < n) ? cnt[i] : 0;
    int x = v;
    #pragma unroll
    for (int d = 1; d < 64; d <<= 1) {
      int y = __shfl_up(x, d);
      if (lane >= d) x += y;
    }
    if (lane == 63) wsum[wid] = x;
    __syncthreads();
    if (wid == 0) {
      int s = (lane < 16) ? wsum[lane] : 0;
      #pragma unroll
      for (int d = 1; d < 16; d <<= 1) {
        int y = __shfl_up(s, d);
        if (lane >= d) s += y;
      }
      if (lane < 16) wsum[lane] = s;
    }
    __syncthreads();
    int waveoff = (wid > 0) ? wsum[wid - 1] : 0;
    int incl = x + waveoff;
    int total = wsum[15];
    int c = carry;
    if (i < n) ofs[i] = c + incl - v;
    __syncthreads();
    if (tid == 0) carry = c + total;
    __syncthreads();
  }
  if (tid == 0) ofs[n] = carry;
}

__global__ void scatter_kernel(const int* __restrict__ ei, int E,
                               const int* __restrict__ ofs, int* __restrict__ cur,
                               int* __restrict__ csr) {
  int e = blockIdx.x * blockDim.x + threadIdx.x;
  if (e < E) {
    int d = ei[E + e];
    int p = ofs[d] + atomicAdd(&cur[d], 1);
    csr[p] = ei[e];  // src
  }
}

// ---------------- CSR sum-aggregation, 4-edge groups ----------------
// Wave per node. g = lane>>4 picks edge within group of 4; q = lane&15 picks
// an 8-feature slice (16B). Cross-group reduce via shfl_xor 16/32. Output
// written as hi/lo bf16 pair (feeds next GEMM at fp32-grade precision).

__global__ __launch_bounds__(256) void agg_kernel(
    const ushort* __restrict__ Xh, const int* __restrict__ csr,
    const int* __restrict__ ofs, ushort* __restrict__ Gh,
    ushort* __restrict__ Gl, int N) {
  int node = (blockIdx.x * blockDim.x + threadIdx.x) >> 6;
  int lane = threadIdx.x & 63;
  if (node >= N) return;
  int g = lane >> 4, q = lane & 15;
  int beg = ofs[node], end = ofs[node + 1];
  float a[8] = {};
  for (int p = beg + g; p < end; p += 4) {
    int s = csr[p];
    short8 v = *(const short8*)(Xh + (size_t)s * 128 + q * 8);
    #pragma unroll
    for (int b = 0; b < 8; ++b) a[b] += b2f((ushort)v[b]);
  }
  #pragma unroll
  for (int b = 0; b < 8; ++b) {
    a[b] += __shfl_xor(a[b], 16);
    a[b] += __shfl_xor(a[b], 32);
  }
  if (lane < 16) {
    short8 h, l;
    #pragma unroll
    for (int b = 0; b < 8; ++b) {
      ushort hh = f2b(a[b]);
      h[b] = (short)hh;
      l[b] = (short)f2b(a[b] - b2f(hh));
    }
    *(short8*)(Gh + (size_t)node * 128 + q * 8) = h;
    *(short8*)(Gl + (size_t)node * 128 + q * 8) = l;
  }
}

// ---------------- bf16x3 MFMA GEMM: C = act(A1@W1 [+ A2@W2] + b) ----------------
// A given as hi/lo bf16 pairs. 512 threads = 8 waves; wave w owns cols
// [16w,16w+16). W column slice split hi/lo in registers (once). 64-row tile
// per block. No LDS, no barriers. a*w ~= al*wh + ah*wl + ah*wh.
// A frag (16x16x32): lane l -> row (l&15), k = (l>>4)*8 + b.
// D frag: col = l&15, row = (l>>4)*4 + reg   [validated rounds 2-3].

template <bool FUSED, bool RELU, bool BIAS>
__global__ __launch_bounds__(512) void mgemm_kernel(
    const ushort* __restrict__ A1h, const ushort* __restrict__ A1l,
    const float* __restrict__ W1,
    const ushort* __restrict__ A2h, const ushort* __restrict__ A2l,
    const float* __restrict__ W2,
    const float* __restrict__ bias,
    ushort* __restrict__ Ch, ushort* __restrict__ Cl, int M) {
  int l = threadIdx.x & 63;
  int w = threadIdx.x >> 6;
  int j = (w << 4) + (l & 15);      // output column
  int krow0 = (l >> 4) * 8;         // k offset within 32-wide k-step
  int rowBase = blockIdx.x * 64;

  // W fragments, compensated split (once per wave): [src][kstep]
  short8 wh[2][4], wl[2][4];
  #pragma unroll
  for (int s = 0; s < (FUSED ? 2 : 1); ++s) {
    const float* W = (s == 0) ? W1 : W2;
    #pragma unroll
    for (int ks = 0; ks < 4; ++ks) {
      short8 fh, fl;
      #pragma unroll
      for (int b = 0; b < 8; ++b) {
        float v = W[(size_t)(ks * 32 + krow0 + b) * 128 + j];
        ushort h = f2b(v);
        fh[b] = (short)h;
        fl[b] = (short)f2b(v - b2f(h));
      }
      wh[s][ks] = fh;
      wl[s][ks] = fl;
    }
  }

  f32x4 acc[4] = {{0.f, 0.f, 0.f, 0.f}, {0.f, 0.f, 0.f, 0.f},
                  {0.f, 0.f, 0.f, 0.f}, {0.f, 0.f, 0.f, 0.f}};

  #pragma unroll
  for (int rf = 0; rf < 4; ++rf) {
    int row = rowBase + rf * 16 + (l & 15);
    if (row >= M) row = M - 1;                 // clamp (tail); writes are masked
    size_t base = (size_t)row * 128 + krow0;
    #pragma unroll
    for (int s = 0; s < (FUSED ? 2 : 1); ++s) {
      const ushort* Ah = (s == 0) ? A1h : A2h;
      const ushort* Al = (s == 0) ? A1l : A2l;
      #pragma unroll
      for (int ks = 0; ks < 4; ++ks) {
        short8 ah = *(const short8*)(Ah + base + ks * 32);
        short8 al = *(const short8*)(Al + base + ks * 32);
        acc[rf] = __builtin_amdgcn_mfma_f32_16x16x32_bf16(al, wh[s][ks], acc[rf], 0, 0, 0);
        acc[rf] = __builtin_amdgcn_mfma_f32_16x16x32_bf16(ah, wl[s][ks], acc[rf], 0, 0, 0);
        acc[rf] = __builtin_amdgcn_mfma_f32_16x16x32_bf16(ah, wh[s][ks], acc[rf], 0, 0, 0);
      }
    }
  }

  float bj = BIAS ? bias[j] : 0.f;
  #pragma unroll
  for (int rf = 0; rf < 4; ++rf) {
    int rbase = rowBase + rf * 16 + (l >> 4) * 4;
    #pragma unroll
    for (int r = 0; r < 4; ++r) {
      int row = rbase + r;
      if (row < M) {
        float v = acc[rf][r];
        if (BIAS) v += bj;
        if (RELU) v = fmaxf(v, 0.f);
        ushort h = f2b(v);
        Ch[(size_t)row * 128 + j] = h;
        Cl[(size_t)row * 128 + j] = f2b(v - b2f(h));
      }
    }
  }
}

// ---------------- per-node dots: s_src = ht.a_src, s_dst = ht.a_dst ----------------
// Reconstructs ht = hi + lo (fp32-grade). Lane handles features 2l, 2l+1.

__global__ __launch_bounds__(256) void dots_kernel(
    const ushort* __restrict__ HTh, const ushort* __restrict__ HTl,
    const float* __restrict__ a_src, const float* __restrict__ a_dst,
    float* __restrict__ ssrc, float* __restrict__ sdst, int N) {
  int n = (blockIdx.x * blockDim.x + threadIdx.x) >> 6;
  int lane = threadIdx.x & 63;
  if (n >= N) return;
  uint uh = ((const uint*)(HTh + (size_t)n * 128))[lane];
  uint ul = ((const uint*)(HTl + (size_t)n * 128))[lane];
  float h0 = b2f((ushort)(uh & 0xffff)) + b2f((ushort)(ul & 0xffff));
  float h1 = b2f((ushort)(uh >> 16)) + b2f((ushort)(ul >> 16));
  float as0 = a_src[2 * lane], as1 = a_src[2 * lane + 1];
  float ad0 = a_dst[2 * lane], ad1 = a_dst[2 * lane + 1];
  float vs = h0 * as0 + h1 * as1;
  float vd = h0 * ad0 + h1 * ad1;
  #pragma unroll
  for (int d = 32; d > 0; d >>= 1) {
    vs += __shfl_xor(vs, d);
    vd += __shfl_xor(vd, d);
  }
  if (lane == 0) { ssrc[n] = vs; sdst[n] = vd; }
}

// ---------------- fused attention: segment softmax + weighted PV ----------------

__global__ __launch_bounds__(256) void attn_kernel(
    const ushort* __restrict__ HTh, const int* __restrict__ csr,
    const int* __restrict__ ofs, const float* __restrict__ ssrc,
    const float* __restrict__ sdst, float* __restrict__ outh, int N) {
  int n = (blockIdx.x * blockDim.x + threadIdx.x) >> 6;
  int lane = threadIdx.x & 63;
  if (n >= N) return;
  int beg = ofs[n], end = ofs[n + 1];
  float sd = sdst[n];

  // phase 1: segment max (lanes over edges)
  float mymax = -3.4e38f;
  for (int p = beg + lane; p < end; p += 64) {
    float e = ssrc[csr[p]] + sd;
    e = (e >= 0.f) ? e : 0.2f * e;
    mymax = fmaxf(mymax, e);
  }
  #pragma unroll
  for (int d = 32; d > 0; d >>= 1) mymax = fmaxf(mymax, __shfl_xor(mymax, d));

  // phase 2: denom
  float mysum = 0.f;
  for (int p = beg + lane; p < end; p += 64) {
    float e = ssrc[csr[p]] + sd;
    e = (e >= 0.f) ? e : 0.2f * e;
    mysum += __expf(e - mymax);
  }
  #pragma unroll
  for (int d = 32; d > 0; d >>= 1) mysum += __shfl_xor(mysum, d);
  float inv = 1.0f / (mysum + 1e-16f);

  // phase 3: weighted PV, 4-edge groups with 16B loads
  int g = lane >> 4, q = lane & 15;
  float a[8] = {};
  for (int p = beg + g; p < end; p += 4) {
    int s = csr[p];
    float e = ssrc[s] + sd;
    e = (e >= 0.f) ? e : 0.2f * e;
    float wgt = __expf(e - mymax) * inv;
    short8 v = *(const short8*)(HTh + (size_t)s * 128 + q * 8);
    #pragma unroll
    for (int b = 0; b < 8; ++b) a[b] += wgt * b2f((ushort)v[b]);
  }
  #pragma unroll
  for (int b = 0; b < 8; ++b) {
    a[b] += __shfl_xor(a[b], 16);
    a[b] += __shfl_xor(a[b], 32);
  }
  if (lane < 16) {
    float4 o0 = {a[0], a[1], a[2], a[3]};
    float4 o1 = {a[4], a[5], a[6], a[7]};
    *(float4*)(outh + (size_t)n * 128 + q * 8) = o0;
    *(float4*)(outh + (size_t)n * 128 + q * 8 + 4) = o1;
  }
}

// ---------------- final FC: out = out_h @ Wfc + bfc  (128 -> 2) ----------------

__global__ __launch_bounds__(256) void fc_kernel(
    const float* __restrict__ H, const float* __restrict__ Wfc,
    const float* __restrict__ bfc, float* __restrict__ out, int N) {
  int n = (blockIdx.x * blockDim.x + threadIdx.x) >> 6;
  int lane = threadIdx.x & 63;
  if (n >= N) return;
  float h0 = H[(size_t)n * 128 + lane];
  float h1 = H[(size_t)n * 128 + 64 + lane];
  float o0 = h0 * Wfc[lane * 2 + 0] + h1 * Wfc[(lane + 64) * 2 + 0];
  float o1 = h0 * Wfc[lane * 2 + 1] + h1 * Wfc[(lane + 64) * 2 + 1];
  #pragma unroll
  for (int d = 32; d > 0; d >>= 1) {
    o0 += __shfl_xor(o0, d);
    o1 += __shfl_xor(o1, d);
  }
  if (lane == 0) {
    out[(size_t)n * 2 + 0] = o0 + bfc[0];
    out[(size_t)n * 2 + 1] = o1 + bfc[1];
  }
}

// ---------------- launch ----------------

static inline size_t align_up(size_t x, size_t a) { return (x + a - 1) & ~(a - 1); }

extern "C" void kernel_launch(void* const* d_in, const int* in_sizes, int n_in,
                              void* d_out, int out_size, void* d_ws, size_t ws_size,
                              hipStream_t stream) {
  const float* x     = (const float*)d_in[0];
  const int*   ei    = (const int*)d_in[1];
  const float* W1r   = (const float*)d_in[2];
  const float* W1n   = (const float*)d_in[3];
  const float* b1    = (const float*)d_in[4];
  const float* W2r   = (const float*)d_in[5];
  const float* W2n   = (const float*)d_in[6];
  const float* b2    = (const float*)d_in[7];
  const float* Wa    = (const float*)d_in[8];
  const float* a_src = (const float*)d_in[9];
  const float* a_dst = (const float*)d_in[10];
  const float* Wfc   = (const float*)d_in[11];
  const float* bfc   = (const float*)d_in[12];

  const int N = in_sizes[0] / 128;   // 50000
  const int E = in_sizes[1] / 2;     // 800000

  // workspace carve-up
  char* ws = (char*)d_ws;
  size_t off = 0;
  auto take = [&](size_t bytes) {
    char* p = ws + off;
    off = align_up(off + bytes, 256);
    return p;
  };
  const size_t NB = (size_t)N * 128 * 2;  // one bf16 node tensor (12.8 MB)
  int*    ofs  = (int*)take((size_t)(N + 1) * 4);
  int*    cnt  = (int*)take((size_t)N * 4);
  int*    cur  = (int*)take((size_t)N * 4);
  int*    csr  = (int*)take((size_t)E * 4);
  float*  ssrc = (float*)take((size_t)N * 4);
  float*  sdst = (float*)take((size_t)N * 4);
  ushort* bA   = (ushort*)take(NB);   // x_hi  -> h2_hi
  ushort* bB   = (ushort*)take(NB);   // x_lo  -> h2_lo
  ushort* bC   = (ushort*)take(NB);   // g_hi  -> ht_hi
  ushort* bD   = (ushort*)take(NB);   // g_lo  -> ht_lo
  ushort* bE   = (ushort*)take(NB);   // h1_hi -.
  ushort* bF   = (ushort*)take(NB);   // h1_lo  }-> outh (fp32, spans E+F)
  float*  outh = (float*)bE;

  hipMemsetAsync(cnt, 0, (size_t)N * 4, stream);
  hipMemsetAsync(cur, 0, (size_t)N * 4, stream);

  const int edgeBlocks = (E + 255) / 256;
  const int nodeBlocks = (N + 3) / 4;   // 4 waves per 256-thread block
  const int gemmBlocks = (N + 63) / 64;
  const int splitBlocks = (N * 128 / 8 + 255) / 256;

  // x split + CSR build (independent chains)
  split_kernel<<<splitBlocks, 256, 0, stream>>>(x, bA, bB, N * 128);
  hist_kernel<<<edgeBlocks, 256, 0, stream>>>(ei, E, cnt);
  scan_kernel<<<1, 1024, 0, stream>>>(cnt, ofs, N);
  scatter_kernel<<<edgeBlocks, 256, 0, stream>>>(ei, E, ofs, cur, csr);

  // layer 1: agg1 = sum(x_hi); h1 = relu(x@W1r + agg1@W1n + b1)
  agg_kernel<<<nodeBlocks, 256, 0, stream>>>(bA, csr, ofs, bC, bD, N);
  mgemm_kernel<true, true, true><<<gemmBlocks, 512, 0, stream>>>(
      bA, bB, W1r, bC, bD, W1n, b1, bE, bF, N);            // h1 -> E,F

  // layer 2: agg2 = sum(h1_hi); h2 = relu(h1@W2r + agg2@W2n + b2)
  agg_kernel<<<nodeBlocks, 256, 0, stream>>>(bE, csr, ofs, bC, bD, N);
  mgemm_kernel<true, true, true><<<gemmBlocks, 512, 0, stream>>>(
      bE, bF, W2r, bC, bD, W2n, b2, bA, bB, N);            // h2 -> A,B (x dead)

  // attention transform: ht = h2@Wa -> C,D (g dead)
  mgemm_kernel<false, false, false><<<gemmBlocks, 512, 0, stream>>>(
      bA, bB, Wa, nullptr, nullptr, nullptr, nullptr, bC, bD, N);
  dots_kernel<<<nodeBlocks, 256, 0, stream>>>(bC, bD, a_src, a_dst, ssrc, sdst, N);
  attn_kernel<<<nodeBlocks, 256, 0, stream>>>(bC, csr, ofs, ssrc, sdst, outh, N);  // outh over E,F (h1 dead)

  // output FC
  fc_kernel<<<nodeBlocks, 256, 0, stream>>>(outh, Wfc, bfc, (float*)d_out, N);
}